// Round 1
// baseline (186.072 us; speedup 1.0000x reference)
//
#include <hip/hip_runtime.h>
#include <hip/hip_bf16.h>
#include <stdint.h>

// out = x @ (W_shared + W_expert)^T + bias   (MoE collapses: positional routing,
// shared expert weights, normalized top-2 gate weights sum to 1)
static constexpr int Mdim = 16384;  // T = B*N tokens
static constexpr int Ndim = 1024;
static constexpr int Kdim = 1024;
static constexpr int BM = 128, BN = 128, BK = 32;  // BK=32, double-buffered

typedef __attribute__((ext_vector_type(8))) __bf16 bf16x8;
typedef __attribute__((ext_vector_type(4))) float f32x4;
typedef __attribute__((ext_vector_type(8))) unsigned short ushort8;

__device__ inline unsigned short f2bf_rn(float f) {
    union { float f; uint32_t u; } v; v.f = f;
    uint32_t u = v.u;
    uint32_t r = u + 0x7FFFu + ((u >> 16) & 1u);
    return (unsigned short)(r >> 16);
}

// pack two fp32 -> bf16 pair (round-half-up: 1 add/elem; bias vs RNE is
// tie-cases only, absmax headroom is 3x)
__device__ inline uint32_t pack_bf2(float a, float b) {
    union { float f; uint32_t u; } ua, ub;
    ua.f = a; ub.f = b;
    uint32_t x = ua.u + 0x8000u;
    uint32_t y = ub.u + 0x8000u;
    return (x >> 16) | (y & 0xFFFF0000u);
}

// Wc = bf16(W_shared + W_expert), 8 elems/thread
__global__ __launch_bounds__(256) void cvt_w_kernel(const float* __restrict__ ws,
                                                    const float* __restrict__ we,
                                                    unsigned short* __restrict__ wc) {
    const size_t i = ((size_t)blockIdx.x * 256 + threadIdx.x) * 8;
    const f32x4* p0 = (const f32x4*)(ws + i);
    const f32x4* p1 = (const f32x4*)(we + i);
    f32x4 a0 = p0[0], a1 = p0[1], b0 = p1[0], b1 = p1[1];
    ushort8 o;
    o[0] = f2bf_rn(a0[0] + b0[0]); o[1] = f2bf_rn(a0[1] + b0[1]);
    o[2] = f2bf_rn(a0[2] + b0[2]); o[3] = f2bf_rn(a0[3] + b0[3]);
    o[4] = f2bf_rn(a1[0] + b1[0]); o[5] = f2bf_rn(a1[1] + b1[1]);
    o[6] = f2bf_rn(a1[2] + b1[2]); o[7] = f2bf_rn(a1[3] + b1[3]);
    *(ushort8*)(wc + i) = o;
}

__device__ inline void gload16(const void* g, void* l) {
    __builtin_amdgcn_global_load_lds((const __attribute__((address_space(1))) void*)g,
                                     (__attribute__((address_space(3))) void*)l,
                                     16, 0, 0);
}

// C[m][n] = sum_k bf16(X[m][k]) * Wc[n][k] + bias[n]
// A (=X) fp32 in global, converted to bf16 in-register during staging.
// Double-buffered 1-deep prefetch: tile t+1's A-reg loads + B global_load_lds
// are issued BEFORE tile t's MFMAs; A pack/ds_write after the MFMAs; one
// barrier per K-step. A-loads issued before B so the pack wait is vmcnt(2),
// not a full drain. LDS layout per buffer: [row][32] bf16 (64-B row stride),
// identical bank behavior + staging maps to the verified single-buffer kernel.
// Grid swizzle: bm-fastest => the 8 bn-blocks of one m-stripe share an XCD L2.
__global__ __launch_bounds__(256, 4) void gemm_fused(const float* __restrict__ X,
                                                     const unsigned short* __restrict__ Bt,
                                                     const float* __restrict__ bias,
                                                     float* __restrict__ C) {
    __shared__ unsigned short As[2 * BM * BK];  // 2 x 8 KiB
    __shared__ unsigned short Bs[2 * BN * BK];  // 2 x 8 KiB

    const int tid = threadIdx.x;
    const int wave = tid >> 6;
    const int lane = tid & 63;
    const int bid = blockIdx.x;
    const int bm = bid & 127;   // fastest -> bid%8 == bm%8 -> same XCD per m-stripe
    const int bn = bid >> 7;
    const int wm = (wave >> 1) * 64;
    const int wn = (wave & 1) * 64;

    // ---- B staging map (8 x 1-KiB chunks per buffer, 2 per wave) ----
    const int cw0 = wave, cw1 = wave + 4;
    const int brow0 = cw0 * 16 + (lane >> 2);
    const int brow1 = cw1 * 16 + (lane >> 2);
    const int bcol = (lane & 3) * 8;
    const unsigned short* gB0 = Bt + (size_t)(bn * BN + brow0) * Kdim + bcol;
    const unsigned short* gB1 = Bt + (size_t)(bn * BN + brow1) * Kdim + bcol;
    unsigned short* lB0 = Bs + cw0 * 512 + lane * 8;   // + buf*4096
    unsigned short* lB1 = Bs + cw1 * 512 + lane * 8;

    // ---- A staging map (fp32 -> bf16 via VGPRs) ----
    const int arow = tid >> 3;        // 0..31 (plus u*32)
    const int acol4 = tid & 7;        // float4 index within 32-col tile
    const float* gA = X + (size_t)(bm * BM + arow) * Kdim + acol4 * 4;
    unsigned short* lA = As + arow * 32 + acol4 * 4;   // + buf*4096 + u*1024

    const int fr = lane & 15;
    const int fq = lane >> 4;
    const int fk = fq * 8;

    f32x4 acc[4][4] = {};
    f32x4 av[4];

    // ---- prologue: stage tile 0 into buffer 0 ----
#pragma unroll
    for (int u = 0; u < 4; ++u)
        av[u] = *(const f32x4*)(gA + (size_t)u * 32 * Kdim);
    gload16(gB0, lB0);
    gload16(gB1, lB1);
#pragma unroll
    for (int u = 0; u < 4; ++u) {
        uint2 w;
        w.x = pack_bf2(av[u][0], av[u][1]);
        w.y = pack_bf2(av[u][2], av[u][3]);
        *(uint2*)(lA + u * 1024) = w;
    }
    __syncthreads();

    int cur = 0;
    for (int kt = 0; kt < Kdim; kt += BK) {
        const int nxt = cur ^ 1;
        const bool pf = (kt + BK < Kdim);
        if (pf) {
            // A-reg loads first (pack below then waits vmcnt(2), B still in flight)
#pragma unroll
            for (int u = 0; u < 4; ++u)
                av[u] = *(const f32x4*)(gA + (size_t)u * 32 * Kdim + kt + BK);
            gload16(gB0 + kt + BK, lB0 + nxt * 4096);
            gload16(gB1 + kt + BK, lB1 + nxt * 4096);
        }

        // ---- compute on buffer cur ----
        const unsigned short* Ac = As + cur * 4096;
        const unsigned short* Bc = Bs + cur * 4096;
        bf16x8 af[4], bfr[4];
#pragma unroll
        for (int i = 0; i < 4; ++i)
            af[i] = *(const bf16x8*)(Ac + (wm + i * 16 + fr) * 32 + fk);
#pragma unroll
        for (int j = 0; j < 4; ++j)
            bfr[j] = *(const bf16x8*)(Bc + (wn + j * 16 + fr) * 32 + fk);
#pragma unroll
        for (int i = 0; i < 4; ++i)
#pragma unroll
            for (int j = 0; j < 4; ++j)
                acc[i][j] = __builtin_amdgcn_mfma_f32_16x16x32_bf16(af[i], bfr[j], acc[i][j], 0, 0, 0);

        if (pf) {
#pragma unroll
            for (int u = 0; u < 4; ++u) {
                uint2 w;
                w.x = pack_bf2(av[u][0], av[u][1]);
                w.y = pack_bf2(av[u][2], av[u][3]);
                *(uint2*)(lA + nxt * 4096 + u * 1024) = w;
            }
        }
        __syncthreads();   // drains own gload_lds (vmcnt) + ds_writes (lgkm)
        cur = nxt;
    }

    // Epilogue: C/D layout col = lane&15, row = (lane>>4)*4 + reg  [m89-verified]
#pragma unroll
    for (int j = 0; j < 4; ++j) {
        const int col = bn * BN + wn + j * 16 + fr;
        const float bv = bias[col];
#pragma unroll
        for (int i = 0; i < 4; ++i) {
            const int row = bm * BM + wm + i * 16 + fq * 4;
            float* p = C + (size_t)row * Ndim + col;
#pragma unroll
            for (int r = 0; r < 4; ++r)
                p[(size_t)r * Ndim] = acc[i][j][r] + bv;
        }
    }
}

extern "C" void kernel_launch(void* const* d_in, const int* in_sizes, int n_in,
                              void* d_out, int out_size, void* d_ws, size_t ws_size,
                              hipStream_t stream) {
    // inputs: x, cond, mask, W_shared, W_expert, W_gate, bias
    const float* x    = (const float*)d_in[0];
    const float* Wsh  = (const float*)d_in[3];
    const float* Wex  = (const float*)d_in[4];
    const float* bias = (const float*)d_in[6];
    float* out = (float*)d_out;

    unsigned short* Wbf = (unsigned short*)d_ws;  // 1024*1024 bf16 = 2 MiB

    hipLaunchKernelGGL(cvt_w_kernel, dim3((Ndim * Kdim) / (256 * 8)), dim3(256), 0, stream,
                       Wsh, Wex, Wbf);
    hipLaunchKernelGGL(gemm_fused, dim3((Mdim / BM) * (Ndim / BN)), dim3(256), 0, stream,
                       x, Wbf, bias, out);
}